// Round 1
// 1580.776 us; speedup vs baseline: 1.0175x; 1.0175x over previous
//
#include <hip/hip_runtime.h>

// GRU B=256,T=2000,I=23,H=128 (gate order r,z,n) + mean over T.
// 1 batch row per block, 256 blocks (1/CU). 512 threads = 8 waves.
//
// Restructure vs previous round: wave w owns h-rows j in [16w,16w+16) and
// computes ALL THREE gates (r,z,n) for them. The k-fold, the r/z/n
// combination, and the h update all complete in-wave:
//   lane = (kt = l&15 : k-tile of 8, gr = l>>4 : j-subgroup of 4)
//   per lane: 8 r/z-gate dots (8k) + 4 n-gate dots (8k) = 96 FMAs.
// XOR-permuted folds leave, on even-kt lanes, r[m], ghn[m], gxn[m] for the
// SAME m, with z[m] on the xor-1 neighbor (one quad_perm DPP away).
// => epilogue fully in-register (no rec[]/gxn[] LDS round-trip), h kept
// double-buffered in LDS => ONE __syncthreads() per step (was 2).

#define Bb 256
#define Tt 2000
#define Ii 23
#define Hh 128

template <int ctrl>
__device__ __forceinline__ float dpp_movf(float v) {
    int r = __builtin_amdgcn_update_dpp(0, __builtin_bit_cast(int, v),
                                        ctrl, 0xf, 0xf, true);
    return __builtin_bit_cast(float, r);
}

// Fold 8 values over the 16 kt-lanes, XOR-permuted: lane ends with the
// complete sum of virtual gate index p(kt) = ((kt&1)<<2)|(kt&2)|((kt>>2)&1).
__device__ __forceinline__ float fold16x8(const float a[8]) {
    float b0 = a[0] + dpp_movf<0xB1>(a[4]);   // xor1 (quad_perm [1,0,3,2])
    float b1 = a[1] + dpp_movf<0xB1>(a[5]);
    float b2 = a[2] + dpp_movf<0xB1>(a[6]);
    float b3 = a[3] + dpp_movf<0xB1>(a[7]);
    float c0 = b0 + dpp_movf<0x4E>(b2);       // xor2 (quad_perm [2,3,0,1])
    float c1 = b1 + dpp_movf<0x4E>(b3);
    float d  = c0 + __shfl_xor(c1, 4, 64);    // xor4 (only DS-pipe hop)
    return d + dpp_movf<0x128>(d);            // xor8 (row_ror:8)
}

// Fold 4 values over the 16 kt-lanes: lane ends with the complete sum of
// virtual gate index p2(kt) = (kt&2)|((kt>>2)&1).  (p2 == p on even kt.)
__device__ __forceinline__ float fold16x4(const float a[4]) {
    float b0 = a[0] + dpp_movf<0xB1>(a[0]);   // xor1: lane-only fold
    float b1 = a[1] + dpp_movf<0xB1>(a[1]);
    float b2 = a[2] + dpp_movf<0xB1>(a[2]);
    float b3 = a[3] + dpp_movf<0xB1>(a[3]);
    float c0 = b0 + dpp_movf<0x4E>(b2);       // xor2 folds value-bit1
    float c1 = b1 + dpp_movf<0x4E>(b3);
    float d  = c0 + __shfl_xor(c1, 4, 64);    // xor4 folds value-bit0
    return d + dpp_movf<0x128>(d);            // xor8 symmetric
}

__global__ __launch_bounds__(512, 2)
void gru_fused(const float* __restrict__ x,     // [B,T,I]
               const float* __restrict__ W_ih,  // [3H,I]
               const float* __restrict__ W_hh,  // [3H,H]
               const float* __restrict__ b_ih,  // [3H]
               const float* __restrict__ b_hh,  // [3H]
               float* __restrict__ out)         // [B,H]
{
    const int b    = blockIdx.x;
    const int t    = threadIdx.x;
    const int wid  = t >> 6;            // 0..7
    const int l    = t & 63;
    const int kt   = l & 15;            // k in [kt*8, kt*8+8)
    const int gr   = l >> 4;            // 0..3
    const int kb   = kt * 8;
    const int p    = ((kt & 1) << 2) | (kt & 2) | ((kt >> 2) & 1);
    const int p2   = (kt & 2) | ((kt >> 2) & 1);
    const int jbase = wid * 16 + gr * 4;        // this group's 4 h-rows

    __shared__ __align__(16) float h_db[2][16][12]; // double-buffered h
    __shared__ float xbuf[2][24];                    // double-buffered x_t

    // ---- r/z weights: slot i <-> gate grz(i^p) (u>>2: 0=r,1=z) ----
    float wrz[8][8];
    #pragma unroll
    for (int i = 0; i < 8; ++i) {
        const int u = i ^ p;
        const int g = (u >> 2) * Hh + jbase + (u & 3);
        #pragma unroll
        for (int k = 0; k < 8; ++k)
            wrz[i][k] = W_hh[(size_t)g * Hh + kb + k];
    }
    // ---- n weights: slot q <-> gate 2H + jbase + (q^p2) ----
    float wn[4][8];
    #pragma unroll
    for (int q = 0; q < 4; ++q) {
        const int g = 2 * Hh + jbase + (q ^ p2);
        #pragma unroll
        for (int k = 0; k < 8; ++k)
            wn[q][k] = W_hh[(size_t)g * Hh + kb + k];
    }

    // x-projection: lane kt covers x indices [xi0, xi0+xcnt)
    const int xi0  = (kt < 7) ? kt * 2 : 14 + (kt - 7);
    const int xcnt = (kt < 7) ? 2 : 1;
    float wxrz[8][2];
    #pragma unroll
    for (int i = 0; i < 8; ++i) {
        const int u = i ^ p;
        const int g = (u >> 2) * Hh + jbase + (u & 3);
        wxrz[i][0] = W_ih[(size_t)g * Ii + xi0];
        wxrz[i][1] = (xcnt > 1) ? W_ih[(size_t)g * Ii + xi0 + 1] : 0.0f;
    }
    float wxn[4][2];
    #pragma unroll
    for (int q = 0; q < 4; ++q) {
        const int g = 2 * Hh + jbase + (q ^ p2);
        wxn[q][0] = W_ih[(size_t)g * Ii + xi0];
        wxn[q][1] = (xcnt > 1) ? W_ih[(size_t)g * Ii + xi0 + 1] : 0.0f;
    }

    // biases: added once per gate, on the kt==0 lane (p==0, p2==0 there)
    float brz[8], bn[4], bxn[4];
    #pragma unroll
    for (int i = 0; i < 8; ++i) {
        const int g = (i >> 2) * Hh + jbase + (i & 3);
        brz[i] = (kt == 0) ? (b_ih[g] + b_hh[g]) : 0.0f;
    }
    #pragma unroll
    for (int q = 0; q < 4; ++q) {
        const int g = 2 * Hh + jbase + q;
        bn[q]  = (kt == 0) ? b_hh[g] : 0.0f;   // recurrent n-sum bias
        bxn[q] = (kt == 0) ? b_ih[g] : 0.0f;   // x-side n-sum bias
    }

    const float* xrow = x + (size_t)b * Tt * Ii;

    // ---- init ----
    if (t < Hh) h_db[0][t >> 3][t & 7] = 0.0f;
    if (t < Ii) xbuf[0][t] = xrow[t];
    if (t == Ii) { xbuf[0][23] = 0.0f; xbuf[1][23] = 0.0f; }
    const bool writer = ((kt & 9) == 0);   // kt in {0,2,4,6}: p in {0,2,1,3}
    const int  jw = jbase + p;             // this writer's h-row
    float h_reg = 0.0f, acc_mean = 0.0f;
    __syncthreads();

    for (int step = 0; step < Tt; ++step) {
        const int cur = step & 1;

        // prefetch next x_t (hidden under the dot)
        float xpref = 0.0f;
        if (t < Ii && step + 1 < Tt) xpref = xrow[(size_t)(step + 1) * Ii + t];

        // ---- load h tile: 8 floats via 2x float4 ----
        const float4 hA = *reinterpret_cast<const float4*>(&h_db[cur][kt][0]);
        const float4 hB = *reinterpret_cast<const float4*>(&h_db[cur][kt][4]);
        const float hv[8] = {hA.x, hA.y, hA.z, hA.w, hB.x, hB.y, hB.z, hB.w};

        // ---- recurrent MACs: 8 r/z gates + 4 n gates, 8 k each ----
        float arz[8];
        #pragma unroll
        for (int i = 0; i < 8; ++i) arz[i] = brz[i];
        float an[4];
        #pragma unroll
        for (int q = 0; q < 4; ++q) an[q] = bn[q];
        #pragma unroll
        for (int k = 0; k < 8; ++k) {
            #pragma unroll
            for (int i = 0; i < 8; ++i)
                arz[i] = fmaf(wrz[i][k], hv[k], arz[i]);
            #pragma unroll
            for (int q = 0; q < 4; ++q)
                an[q] = fmaf(wn[q][k], hv[k], an[q]);
        }

        // ---- x projection ----
        const float xa = xbuf[cur][xi0];
        const float xb = xbuf[cur][xi0 + 1];
        #pragma unroll
        for (int i = 0; i < 8; ++i)
            arz[i] = fmaf(wxrz[i][0], xa, fmaf(wxrz[i][1], xb, arz[i]));
        float axn[4];
        #pragma unroll
        for (int q = 0; q < 4; ++q)
            axn[q] = fmaf(wxn[q][0], xa, fmaf(wxn[q][1], xb, bxn[q]));

        // ---- folds: all gate sums complete in-wave ----
        const float rz  = fold16x8(arz);    // lane holds r/z virtual gate p
        const float ghn = fold16x4(an);     // lane holds ghn[p2]
        const float gxn = fold16x4(axn);    // lane holds gxn[p2]

        // stage next x into alternate buffer
        if (t < Ii && step + 1 < Tt) xbuf[cur ^ 1][t] = xpref;

        // ---- in-register epilogue (valid on even-kt lanes) ----
        // even kt: rz = r[m], ghn/gxn at same m; z[m] on xor-1 neighbor.
        const float zin  = dpp_movf<0xB1>(rz);
        const float r    = 1.0f / (1.0f + __expf(-rz));
        const float z    = 1.0f / (1.0f + __expf(-zin));
        const float npre = fmaf(r, ghn, gxn);
        const float n    = 2.0f / (1.0f + __expf(-2.0f * npre)) - 1.0f;
        const float h_new = fmaf(z, h_reg - n, n);
        if (writer) {
            acc_mean += h_new;
            h_reg = h_new;
            h_db[cur ^ 1][jw >> 3][jw & 7] = h_new;
        }
        __syncthreads();   // the ONLY barrier per step
    }

    if (writer) out[(size_t)b * Hh + jw] = acc_mean * (1.0f / Tt);
}

extern "C" void kernel_launch(void* const* d_in, const int* in_sizes, int n_in,
                              void* d_out, int out_size, void* d_ws, size_t ws_size,
                              hipStream_t stream) {
    const float* x    = (const float*)d_in[0];
    const float* W_ih = (const float*)d_in[1];
    const float* W_hh = (const float*)d_in[2];
    const float* b_ih = (const float*)d_in[3];
    const float* b_hh = (const float*)d_in[4];
    float* out = (float*)d_out;

    gru_fused<<<Bb, 512, 0, stream>>>(x, W_ih, W_hh, b_ih, b_hh, out);
}

// Round 2
// 1332.911 us; speedup vs baseline: 1.2067x; 1.1860x over previous
//
#include <hip/hip_runtime.h>

// GRU B=256,T=2000,I=23,H=128 (gate order r,z,n) + mean over T.
// 1 batch row per block, 256 blocks (1/CU). 512 threads = 8 waves, 2/SIMD.
//
// v3 (this round) vs v2:
//  - x-side gate projections gx[t] = W_ih x_t + b_ih (+ b_hh for r,z) are
//    produced ONE STEP AHEAD, gate-per-lane (23 FMA, no folds), into LDS
//    gxl[2][3][128] (plane-separated: conflict-free b32 writes/reads).
//    Removes per-lane x-proj (24 FMA) + the gxn fold16x4 (15 instr).
//    Lanes >=384 duplicate r-gates (same-addr same-value writes, benign)
//    so production is wave-uniform, no divergence.
//  - all 1/(1+e) via v_rcp_f32 (__builtin_amdgcn_rcpf): the previous
//    1.0f/(1+e) compiled to the ~7-instr IEEE div expansion, x3/step.
//  - __shfl_xor(.,4) -> ds_swizzle offset 0x101F (xor4), 1 DS op.
//  - x staging on wave-6 lanes, depth-2 prefetch into a ring-4 xbuf so the
//    global-load latency never gates the per-step barrier.

#define Bb 256
#define Tt 2000
#define Ii 23
#define Hh 128

template <int N> struct ic { static constexpr int v = N; };

template <int ctrl>
__device__ __forceinline__ float dpp_movf(float v) {
    int r = __builtin_amdgcn_update_dpp(0, __builtin_bit_cast(int, v),
                                        ctrl, 0xf, 0xf, true);
    return __builtin_bit_cast(float, r);
}
__device__ __forceinline__ float swz_xor4(float v) {
    int r = __builtin_amdgcn_ds_swizzle(__builtin_bit_cast(int, v), 0x101F);
    return __builtin_bit_cast(float, r);
}

// fold 8 accs over 16 kt-lanes, XOR-permuted: lane ends with full sum of
// virtual slot p(kt) = ((kt&1)<<2)|(kt&2)|((kt>>2)&1).
__device__ __forceinline__ float fold16x8(const float a[8]) {
    float b0 = a[0] + dpp_movf<0xB1>(a[4]);   // xor1 (quad_perm [1,0,3,2])
    float b1 = a[1] + dpp_movf<0xB1>(a[5]);
    float b2 = a[2] + dpp_movf<0xB1>(a[6]);
    float b3 = a[3] + dpp_movf<0xB1>(a[7]);
    float c0 = b0 + dpp_movf<0x4E>(b2);       // xor2 (quad_perm [2,3,0,1])
    float c1 = b1 + dpp_movf<0x4E>(b3);
    float d  = c0 + swz_xor4(c1);             // xor4 (only DS hop)
    return d + dpp_movf<0x128>(d);            // xor8 (row_ror:8)
}
// fold 4 accs over 16 kt-lanes: lane ends with full sum of slot
// p2(kt) = (kt&2)|((kt>>2)&1).
__device__ __forceinline__ float fold16x4(const float a[4]) {
    float b0 = a[0] + dpp_movf<0xB1>(a[0]);
    float b1 = a[1] + dpp_movf<0xB1>(a[1]);
    float b2 = a[2] + dpp_movf<0xB1>(a[2]);
    float b3 = a[3] + dpp_movf<0xB1>(a[3]);
    float c0 = b0 + dpp_movf<0x4E>(b2);
    float c1 = b1 + dpp_movf<0x4E>(b3);
    float d  = c0 + swz_xor4(c1);
    return d + dpp_movf<0x128>(d);
}

__global__ __launch_bounds__(512, 2)
void gru_fused(const float* __restrict__ x,     // [B,T,I]
               const float* __restrict__ W_ih,  // [3H,I]
               const float* __restrict__ W_hh,  // [3H,H]
               const float* __restrict__ b_ih,  // [3H]
               const float* __restrict__ b_hh,  // [3H]
               float* __restrict__ out)         // [B,H]
{
    const int b   = blockIdx.x;
    const int t   = threadIdx.x;
    const int wid = t >> 6;
    const int l   = t & 63;
    const int kt  = l & 15;
    const int gr  = l >> 4;
    const int kb  = kt * 8;
    const int p   = ((kt & 1) << 2) | (kt & 2) | ((kt >> 2) & 1);
    const int p2  = (kt & 2) | ((kt >> 2) & 1);
    const int jbase = wid * 16 + gr * 4;
    const int jg  = jbase + (p & 3);

    __shared__ __align__(16) float h_db[2][16][12];  // double-buffered h
    __shared__ __align__(16) float gxl[2][3][128];   // [par][r,z,n][j]
    __shared__ __align__(16) float xbuf[4][24];      // ring-4 x rows

    // ---- recurrent weights (per-lane register tiles, as v2) ----
    float wrz[8][8];
    #pragma unroll
    for (int i = 0; i < 8; ++i) {
        const int u = i ^ p;
        const int g = (u >> 2) * Hh + jbase + (u & 3);
        #pragma unroll
        for (int k = 0; k < 8; ++k)
            wrz[i][k] = W_hh[(size_t)g * Hh + kb + k];
    }
    float wn[4][8];
    #pragma unroll
    for (int q = 0; q < 4; ++q) {
        const int g = 2 * Hh + jbase + (q ^ p2);
        #pragma unroll
        for (int k = 0; k < 8; ++k)
            wn[q][k] = W_hh[(size_t)g * Hh + kb + k];
    }
    const float bhhn = b_hh[2 * Hh + jg];   // n-gate recurrent bias, per-j

    // ---- x-side producer: one gate per lane (lanes>=384 duplicate r) ----
    const int gq = (t < 384) ? t : (t - 384);
    const int pj = gq & 127;
    const int pt = gq >> 7;
    float wih[Ii];
    #pragma unroll
    for (int i = 0; i < Ii; ++i) wih[i] = W_ih[(size_t)gq * Ii + i];
    const float bq = b_ih[gq] + ((gq < 2 * Hh) ? b_hh[gq] : 0.0f);

    const float* xrow = x + (size_t)b * Tt * Ii;

    auto produce_gx = [&](const float* xb) -> float {
        const float4 x0 = *reinterpret_cast<const float4*>(xb + 0);
        const float4 x1 = *reinterpret_cast<const float4*>(xb + 4);
        const float4 x2 = *reinterpret_cast<const float4*>(xb + 8);
        const float4 x3 = *reinterpret_cast<const float4*>(xb + 12);
        const float4 x4 = *reinterpret_cast<const float4*>(xb + 16);
        const float4 x5 = *reinterpret_cast<const float4*>(xb + 20);
        const float xv[24] = {x0.x,x0.y,x0.z,x0.w, x1.x,x1.y,x1.z,x1.w,
                              x2.x,x2.y,x2.z,x2.w, x3.x,x3.y,x3.z,x3.w,
                              x4.x,x4.y,x4.z,x4.w, x5.x,x5.y,x5.z,x5.w};
        float aq = bq;
        #pragma unroll
        for (int i = 0; i < Ii; ++i) aq = fmaf(wih[i], xv[i], aq);
        return aq;
    };

    // ---- stagers: wave 6 lanes 0..22, depth-2 x prefetch ----
    const bool stg = (t >= 384) && (t < 384 + Ii);
    const int  si  = t - 384;
    float xprefE = 0.0f, xprefO = 0.0f;
    if (stg) {
        xbuf[0][si] = xrow[si];
        xbuf[1][si] = xrow[Ii + si];
        xprefE = xrow[2 * Ii + si];     // x[2]
        xprefO = xrow[3 * Ii + si];     // x[3]
    }
    if (t < Hh) h_db[0][t >> 3][t & 7] = 0.0f;
    float h_reg = 0.0f, acc_mean = 0.0f;
    const bool writer = ((kt & 9) == 0);   // kt in {0,2,4,6} -> p in {0,2,1,3}
    const int  jw = jbase + p;
    __syncthreads();

    // produce gx for step 0 from xbuf[0]
    gxl[0][pt][pj] = produce_gx(&xbuf[0][0]);
    __syncthreads();

    auto body = [&](auto CUR, int s) {
        constexpr int cur = decltype(CUR)::v;
        const int step = s + cur;

        // early independent LDS reads
        const float grz = gxl[cur][kt & 1][jg];
        const float gn  = gxl[cur][2][jg];
        const float4 hA = *reinterpret_cast<const float4*>(&h_db[cur][kt][0]);
        const float4 hB = *reinterpret_cast<const float4*>(&h_db[cur][kt][4]);
        const float hv[8] = {hA.x, hA.y, hA.z, hA.w, hB.x, hB.y, hB.z, hB.w};

        // ---- recurrent MACs: 8 r/z + 4 n gates, 8 k each ----
        float arz[8], an[4];
        #pragma unroll
        for (int i = 0; i < 8; ++i) arz[i] = wrz[i][0] * hv[0];
        #pragma unroll
        for (int q = 0; q < 4; ++q) an[q] = wn[q][0] * hv[0];
        #pragma unroll
        for (int k = 1; k < 8; ++k) {
            #pragma unroll
            for (int i = 0; i < 8; ++i) arz[i] = fmaf(wrz[i][k], hv[k], arz[i]);
            #pragma unroll
            for (int q = 0; q < 4; ++q) an[q] = fmaf(wn[q][k], hv[k], an[q]);
        }

        // ---- produce gx for step+1 (wave-uniform, all lanes) ----
        if (step + 1 < Tt)
            gxl[cur ^ 1][pt][pj] = produce_gx(&xbuf[(step + 1) & 3][0]);

        // ---- stage x two steps ahead (wave 6 lanes only) ----
        if (stg) {
            if (step + 2 < Tt)
                xbuf[(step + 2) & 3][si] = cur ? xprefO : xprefE;
            if (step + 4 < Tt) {
                const float v = xrow[(size_t)(step + 4) * Ii + si];
                if (cur) xprefO = v; else xprefE = v;
            }
        }

        // ---- folds (all in-wave) ----
        const float rzf = fold16x8(arz);     // rec r/z sum at virtual slot p
        const float ghn = fold16x4(an);      // rec n sum at slot p2

        // ---- in-register epilogue ----
        const float rz_tot = rzf + grz;                       // + x-side (+biases)
        const float zin = dpp_movf<0xB1>(rz_tot);             // neighbor's z
        const float r  = __builtin_amdgcn_rcpf(1.0f + __expf(-rz_tot));
        const float z  = __builtin_amdgcn_rcpf(1.0f + __expf(-zin));
        const float npre = fmaf(r, ghn + bhhn, gn);
        const float tt2  = __builtin_amdgcn_rcpf(1.0f + __expf(-2.0f * npre));
        const float nn   = fmaf(2.0f, tt2, -1.0f);            // tanh(npre)
        const float h_new = fmaf(z, h_reg - nn, nn);
        h_reg = h_new;
        if (writer) {
            acc_mean += h_new;
            h_db[cur ^ 1][jw >> 3][jw & 7] = h_new;
        }
        __syncthreads();   // the ONLY barrier per step
    };

    for (int s = 0; s < Tt; s += 2) {
        body(ic<0>{}, s);
        body(ic<1>{}, s);
    }

    if (writer) out[(size_t)b * Hh + jw] = acc_mean * (1.0f / Tt);
}

extern "C" void kernel_launch(void* const* d_in, const int* in_sizes, int n_in,
                              void* d_out, int out_size, void* d_ws, size_t ws_size,
                              hipStream_t stream) {
    const float* x    = (const float*)d_in[0];
    const float* W_ih = (const float*)d_in[1];
    const float* W_hh = (const float*)d_in[2];
    const float* b_ih = (const float*)d_in[3];
    const float* b_hh = (const float*)d_in[4];
    float* out = (float*)d_out;

    gru_fused<<<Bb, 512, 0, stream>>>(x, W_ih, W_hh, b_ih, b_hh, out);
}

// Round 3
// 1320.531 us; speedup vs baseline: 1.2180x; 1.0094x over previous
//
#include <hip/hip_runtime.h>

// GRU B=256,T=2000,I=23,H=128 (gate order r,z,n) + mean over T.
// 1 batch row per block, 256 blocks (1/CU). 512 threads = 8 waves, 2/SIMD.
//
// v4 vs v3:
//  - x-side producer/LDS machinery (gxl, xbuf, produce_gx) REMOVED. Each
//    lane loads its own 2 x-values for step+1 straight from global (L1-hot
//    92B row), prefetched one step ahead into registers. r/z x-terms are
//    packed into the recurrent accumulators BEFORE the fold; only the
//    n-gate x-side needs its own fold16x4 (r multiplies the h-side only).
//    DS ops/lane/step: 14 -> 6; the 8.2M gxl bank-conflict cycles vanish.
//  - MAC block uses v_pk_fma_f32 / v_pk_mul_f32 (packed dual fp32, the
//    only path to the 157 TF fp32 peak; compiler never auto-emits it).
//    96+24 scalar FMAs -> 60 pk ops + 16 merge adds.
//  - biases applied post-fold (3 adds), no kt-gated bias-init movs.

#define Bb 256
#define Tt 2000
#define Ii 23
#define Hh 128

typedef float v2f __attribute__((ext_vector_type(2)));
typedef float v4f __attribute__((ext_vector_type(4)));

template <int N> struct ic { static constexpr int v = N; };

template <int ctrl>
__device__ __forceinline__ float dpp_movf(float v) {
    int r = __builtin_amdgcn_update_dpp(0, __builtin_bit_cast(int, v),
                                        ctrl, 0xf, 0xf, true);
    return __builtin_bit_cast(float, r);
}
__device__ __forceinline__ float swz_xor4(float v) {
    int r = __builtin_amdgcn_ds_swizzle(__builtin_bit_cast(int, v), 0x101F);
    return __builtin_bit_cast(float, r);
}
__device__ __forceinline__ void pk_fma(v2f& a, v2f b, v2f c) {
    asm("v_pk_fma_f32 %0, %1, %2, %0" : "+v"(a) : "v"(b), "v"(c));
}
__device__ __forceinline__ v2f pk_mul(v2f b, v2f c) {
    v2f d;
    asm("v_pk_mul_f32 %0, %1, %2" : "=v"(d) : "v"(b), "v"(c));
    return d;
}

// fold 8 accs over 16 kt-lanes, XOR-permuted: lane ends with the full sum
// of virtual slot p(kt) = ((kt&1)<<2)|(kt&2)|((kt>>2)&1).
__device__ __forceinline__ float fold16x8(const float a[8]) {
    float b0 = a[0] + dpp_movf<0xB1>(a[4]);   // xor1 (quad_perm [1,0,3,2])
    float b1 = a[1] + dpp_movf<0xB1>(a[5]);
    float b2 = a[2] + dpp_movf<0xB1>(a[6]);
    float b3 = a[3] + dpp_movf<0xB1>(a[7]);
    float c0 = b0 + dpp_movf<0x4E>(b2);       // xor2 (quad_perm [2,3,0,1])
    float c1 = b1 + dpp_movf<0x4E>(b3);
    float d  = c0 + swz_xor4(c1);             // xor4 (only DS hop)
    return d + dpp_movf<0x128>(d);            // xor8 (row_ror:8)
}
// fold 4 accs over 16 kt-lanes: lane ends with full sum of slot
// p2(kt) = (kt&2)|((kt>>2)&1).
__device__ __forceinline__ float fold16x4(const float a[4]) {
    float b0 = a[0] + dpp_movf<0xB1>(a[0]);
    float b1 = a[1] + dpp_movf<0xB1>(a[1]);
    float b2 = a[2] + dpp_movf<0xB1>(a[2]);
    float b3 = a[3] + dpp_movf<0xB1>(a[3]);
    float c0 = b0 + dpp_movf<0x4E>(b2);
    float c1 = b1 + dpp_movf<0x4E>(b3);
    float d  = c0 + swz_xor4(c1);
    return d + dpp_movf<0x128>(d);
}

__global__ __launch_bounds__(512, 2)
void gru_fused(const float* __restrict__ x,     // [B,T,I]
               const float* __restrict__ W_ih,  // [3H,I]
               const float* __restrict__ W_hh,  // [3H,H]
               const float* __restrict__ b_ih,  // [3H]
               const float* __restrict__ b_hh,  // [3H]
               float* __restrict__ out)         // [B,H]
{
    const int b   = blockIdx.x;
    const int tid = threadIdx.x;
    const int wid = tid >> 6;
    const int l   = tid & 63;
    const int kt  = l & 15;
    const int kb  = kt * 8;
    const int p   = ((kt & 1) << 2) | (kt & 2) | ((kt >> 2) & 1);
    const int p2  = (kt & 2) | ((kt >> 2) & 1);
    const int jbase = wid * 16 + ((l >> 4) << 2);

    __shared__ __align__(16) float h_db[2][16][12];  // double-buffered h

    // ---- recurrent weights as k-pairs (v2f) ----
    v2f wrz2[8][4];
    #pragma unroll
    for (int i = 0; i < 8; ++i) {
        const int u = i ^ p;
        const int g = (u >> 2) * Hh + jbase + (u & 3);
        const v2f* wp = reinterpret_cast<const v2f*>(W_hh + (size_t)g * Hh + kb);
        #pragma unroll
        for (int kk = 0; kk < 4; ++kk) wrz2[i][kk] = wp[kk];
    }
    v2f wn2[4][4];
    #pragma unroll
    for (int q = 0; q < 4; ++q) {
        const int g = 2 * Hh + jbase + (q ^ p2);
        const v2f* wp = reinterpret_cast<const v2f*>(W_hh + (size_t)g * Hh + kb);
        #pragma unroll
        for (int kk = 0; kk < 4; ++kk) wn2[q][kk] = wp[kk];
    }

    // ---- x-side weights: lane kt covers x indices xi0 (+xi0+1 if kt<7) ----
    const int xi0  = (kt < 7) ? kt * 2 : 7 + kt;      // 0..13 / 14..22
    const int xoff = (kt < 7) ? 1 : 0;                // 2nd elem offset (0 = dup, w=0)
    v2f wx2[8];
    #pragma unroll
    for (int i = 0; i < 8; ++i) {
        const int u = i ^ p;
        const int g = (u >> 2) * Hh + jbase + (u & 3);
        wx2[i][0] = W_ih[(size_t)g * Ii + xi0];
        wx2[i][1] = xoff ? W_ih[(size_t)g * Ii + xi0 + 1] : 0.0f;
    }
    v2f wxn2[4];
    #pragma unroll
    for (int q = 0; q < 4; ++q) {
        const int g = 2 * Hh + jbase + (q ^ p2);
        wxn2[q][0] = W_ih[(size_t)g * Ii + xi0];
        wxn2[q][1] = xoff ? W_ih[(size_t)g * Ii + xi0 + 1] : 0.0f;
    }

    // ---- per-lane biases (applied post-fold) ----
    const int gp = (p >> 2) * Hh + jbase + (p & 3);
    const float brz_l = b_ih[gp] + b_hh[gp];
    const int jn = jbase + p2;
    const float bhn_l = b_hh[2 * Hh + jn];
    const float bxn_l = b_ih[2 * Hh + jn];

    const float* xrow = x + (size_t)b * Tt * Ii;

    // ---- init ----
    if (tid < Hh) h_db[0][tid >> 3][tid & 7] = 0.0f;
    float xa = xrow[xi0];
    float xb = xrow[xi0 + xoff];
    float h_reg = 0.0f, acc_mean = 0.0f;
    const bool writer = ((kt & 9) == 0);   // kt in {0,2,4,6} -> p in {0,2,1,3}
    const int  jw = jbase + p;
    __syncthreads();

    auto body = [&](auto CUR, int s) {
        constexpr int cur = decltype(CUR)::v;
        const int step = s + cur;

        // ---- issue x prefetch for step+1 (L1-hot row, VMEM pipe) ----
        const int tn = (step + 1 < Tt) ? (step + 1) : (Tt - 1);
        const float* nx = xrow + (size_t)tn * Ii + xi0;
        const float na = nx[0];
        const float nb = nx[xoff];

        // ---- load h tile: 8 floats as 2x b128, split into pairs ----
        const v4f hA = *reinterpret_cast<const v4f*>(&h_db[cur][kt][0]);
        const v4f hB = *reinterpret_cast<const v4f*>(&h_db[cur][kt][4]);
        v2f hp[4];
        hp[0] = __builtin_shufflevector(hA, hA, 0, 1);
        hp[1] = __builtin_shufflevector(hA, hA, 2, 3);
        hp[2] = __builtin_shufflevector(hB, hB, 0, 1);
        hp[3] = __builtin_shufflevector(hB, hB, 2, 3);

        // ---- packed recurrent MACs: 8 r/z + 4 n gates ----
        v2f acc[8];
        #pragma unroll
        for (int i = 0; i < 8; ++i) acc[i] = pk_mul(wrz2[i][0], hp[0]);
        v2f accn[4];
        #pragma unroll
        for (int q = 0; q < 4; ++q) accn[q] = pk_mul(wn2[q][0], hp[0]);
        #pragma unroll
        for (int kk = 1; kk < 4; ++kk) {
            #pragma unroll
            for (int i = 0; i < 8; ++i) pk_fma(acc[i], wrz2[i][kk], hp[kk]);
            #pragma unroll
            for (int q = 0; q < 4; ++q) pk_fma(accn[q], wn2[q][kk], hp[kk]);
        }

        // ---- x-side: r/z folds into acc; n kept separate ----
        v2f xpv; xpv[0] = xa; xpv[1] = xb;
        #pragma unroll
        for (int i = 0; i < 8; ++i) pk_fma(acc[i], wx2[i], xpv);
        float arz[8];
        #pragma unroll
        for (int i = 0; i < 8; ++i) arz[i] = acc[i][0] + acc[i][1];
        float an[4], axn[4];
        #pragma unroll
        for (int q = 0; q < 4; ++q) {
            an[q] = accn[q][0] + accn[q][1];
            v2f t = pk_mul(wxn2[q], xpv);
            axn[q] = t[0] + t[1];
        }

        // ---- folds (all in-wave) + biases ----
        const float rz_tot = fold16x8(arz) + brz_l;   // r/z pre-act at slot p
        const float ghn = fold16x4(an) + bhn_l;       // rec n-sum at slot p2
        const float gxn = fold16x4(axn) + bxn_l;      // x-side n-sum at slot p2

        // rotate x prefetch
        xa = na; xb = nb;

        // ---- in-register epilogue (valid on even-kt lanes) ----
        const float zin = dpp_movf<0xB1>(rz_tot);     // neighbor's z pre-act
        const float r  = __builtin_amdgcn_rcpf(1.0f + __expf(-rz_tot));
        const float z  = __builtin_amdgcn_rcpf(1.0f + __expf(-zin));
        const float npre = fmaf(r, ghn, gxn);
        const float tt2  = __builtin_amdgcn_rcpf(1.0f + __expf(-2.0f * npre));
        const float nn   = fmaf(2.0f, tt2, -1.0f);    // tanh(npre)
        const float h_new = fmaf(z, h_reg - nn, nn);
        h_reg = h_new;
        if (writer) {
            acc_mean += h_new;
            h_db[cur ^ 1][jw >> 3][jw & 7] = h_new;
        }
        __syncthreads();   // the ONLY barrier per step
    };

    for (int s = 0; s < Tt; s += 2) {
        body(ic<0>{}, s);
        body(ic<1>{}, s);
    }

    if (writer) out[(size_t)b * Hh + jw] = acc_mean * (1.0f / Tt);
}

extern "C" void kernel_launch(void* const* d_in, const int* in_sizes, int n_in,
                              void* d_out, int out_size, void* d_ws, size_t ws_size,
                              hipStream_t stream) {
    const float* x    = (const float*)d_in[0];
    const float* W_ih = (const float*)d_in[1];
    const float* W_hh = (const float*)d_in[2];
    const float* b_ih = (const float*)d_in[3];
    const float* b_hh = (const float*)d_in[4];
    float* out = (float*)d_out;

    gru_fused<<<Bb, 512, 0, stream>>>(x, W_ih, W_hh, b_ih, b_hh, out);
}